// Round 1
// baseline (974.823 us; speedup 1.0000x reference)
//
#include <hip/hip_runtime.h>
#include <math.h>

namespace {
constexpr int H = 512, W = 512, NUM_ANCH = 6;
constexpr int N = H * W * NUM_ANCH;          // 1572864
constexpr int PREK = 4096;
constexpr int POSTK = 500;
constexpr float SCORE_THRESH = 0.1f;
constexpr float IOU_THRESH = 0.01f;
constexpr float DIR_OFFSET = 0.78539f;
constexpr float PERIOD = 3.14159265358979323846f; // f32(pi)
constexpr int LISTB_CAP = 8192;

// ---- workspace byte offsets (all multiples of 8) ----
constexpr size_t oScores = 0;                                  // N f32
constexpr size_t oHist12 = (size_t)N * 4;                      // 4096 u32
constexpr size_t oHistA  = oHist12 + 4096 * 4;                 // 1024 u32
constexpr size_t oHistB  = oHistA + 1024 * 4;                  // 1024 u32
constexpr size_t oMeta   = oHistB + 1024 * 4;                  // 64 u32
constexpr size_t oListAS = oMeta + 64 * 4;                     // PREK f32
constexpr size_t oListAI = oListAS + PREK * 4;                 // PREK u32
constexpr size_t oListB  = oListAI + PREK * 4;                 // LISTB_CAP u32
constexpr size_t oTopS   = oListB + (size_t)LISTB_CAP * 4;     // PREK f32
constexpr size_t oTopI   = oTopS + PREK * 4;                   // PREK u32
constexpr size_t oTB     = oTopI + PREK * 4;                   // PREK*7 f32
constexpr size_t oX1     = oTB + (size_t)PREK * 7 * 4;
constexpr size_t oX2     = oX1 + PREK * 4;
constexpr size_t oY1     = oX2 + PREK * 4;
constexpr size_t oY2     = oY1 + PREK * 4;
constexpr size_t oArea   = oY2 + PREK * 4;
constexpr size_t oLabel  = oArea + PREK * 4;                   // PREK u32
constexpr size_t oKeepW  = oLabel + PREK * 4;                  // 64 u64
constexpr size_t oMask   = oKeepW + 64 * 8;                    // PREK*64 u64
constexpr size_t WS_NEED = oMask + (size_t)PREK * 64 * 8;
// meta slots: 0:T1 1:G1 2:T2 3:G2 12:T3 5:G 6:E 7:cntA 8:cntB 10,11:scratch
}

__device__ __forceinline__ float sigmoid_rn(float x) {
  // correctly-rounded-to-f32 sigmoid via double
  return (float)(1.0 / (1.0 + exp(-(double)x)));
}

// ---- 1: per-anchor score + 12-bit histogram ----
__global__ void k_scores(const float* __restrict__ cls, float* __restrict__ scores,
                         unsigned* __restrict__ hist12) {
  __shared__ unsigned h[4096];
  for (int t = threadIdx.x; t < 4096; t += blockDim.x) h[t] = 0;
  __syncthreads();
  int stride = gridDim.x * blockDim.x;
  for (int n = blockIdx.x * blockDim.x + threadIdx.x; n < N; n += stride) {
    float p0 = sigmoid_rn(cls[n * 3 + 0]);
    float p1 = sigmoid_rn(cls[n * 3 + 1]);
    float p2 = sigmoid_rn(cls[n * 3 + 2]);
    float best = p0;
    if (p1 > best) best = p1;
    if (p2 > best) best = p2;
    float s = (best >= SCORE_THRESH) ? best : 0.0f;
    scores[n] = s;
    atomicAdd(&h[__float_as_uint(s) >> 20], 1u);
  }
  __syncthreads();
  for (int t = threadIdx.x; t < 4096; t += blockDim.x) {
    unsigned v = h[t];
    if (v) atomicAdd(&hist12[t], v);
  }
}

// ---- generic scan: find bin where cumulative-from-top crosses R ----
__global__ void k_scan(const unsigned* __restrict__ hist, unsigned* __restrict__ meta,
                       int nbins, int prevGslot, int outBin, int outG, int outE) {
  __shared__ unsigned part[256];
  int t = threadIdx.x;
  int chunk = nbins >> 8;
  unsigned prevG = (prevGslot >= 0) ? meta[prevGslot] : 0u;
  unsigned R = (unsigned)PREK - prevG;
  unsigned s = 0;
  for (int c = 0; c < chunk; ++c) s += hist[t * chunk + c];
  part[t] = s;
  __syncthreads();
  for (int off = 1; off < 256; off <<= 1) {
    unsigned v = part[t];
    unsigned add = (t + off < 256) ? part[t + off] : 0u;
    __syncthreads();
    part[t] = v + add;
    __syncthreads();
  }
  unsigned cum = (t == 255) ? 0u : part[t + 1];
  for (int c = chunk - 1; c >= 0; --c) {
    unsigned hv = hist[t * chunk + c];
    unsigned above = cum;
    cum += hv;
    if (cum >= R && above < R) {
      meta[outBin] = (unsigned)(t * chunk + c);
      meta[outG] = prevG + above;
      meta[outE] = R - above;
    }
  }
}

// ---- refine histograms (mode 0: bits[19:10] within top-12 bin; mode 1: bits[9:0]) ----
__global__ void k_hist_refine(const float* __restrict__ scores, unsigned* __restrict__ hist,
                              const unsigned* __restrict__ meta, int mode) {
  __shared__ unsigned h[1024];
  for (int t = threadIdx.x; t < 1024; t += blockDim.x) h[t] = 0;
  __syncthreads();
  unsigned m0 = meta[0], m2 = meta[2];
  unsigned pref22 = (m0 << 10) | m2;
  int stride = gridDim.x * blockDim.x;
  for (int n = blockIdx.x * blockDim.x + threadIdx.x; n < N; n += stride) {
    unsigned bits = __float_as_uint(scores[n]);
    if (mode == 0) {
      if ((bits >> 20) == m0) atomicAdd(&h[(bits >> 10) & 1023u], 1u);
    } else {
      if ((bits >> 10) == pref22) atomicAdd(&h[bits & 1023u], 1u);
    }
  }
  __syncthreads();
  for (int t = threadIdx.x; t < 1024; t += blockDim.x) {
    unsigned v = h[t];
    if (v) atomicAdd(&hist[t], v);
  }
}

// ---- compact > thr and == thr ----
__global__ void k_compact(const float* __restrict__ scores, unsigned* __restrict__ meta,
                          float* __restrict__ laS, unsigned* __restrict__ laI,
                          unsigned* __restrict__ lb) {
  unsigned thr = (meta[0] << 20) | (meta[2] << 10) | meta[12];
  int stride = gridDim.x * blockDim.x;
  for (int n = blockIdx.x * blockDim.x + threadIdx.x; n < N; n += stride) {
    float sv = scores[n];
    unsigned bits = __float_as_uint(sv);
    if (bits > thr) {
      unsigned pos = atomicAdd(&meta[7], 1u);
      if (pos < (unsigned)PREK) { laS[pos] = sv; laI[pos] = (unsigned)n; }
    } else if (bits == thr) {
      unsigned pos = atomicAdd(&meta[8], 1u);
      if (pos < (unsigned)LISTB_CAP) lb[pos] = (unsigned)n;
    }
  }
}

// ---- pick lowest-index ties, append to listA ----
__global__ __launch_bounds__(1024) void k_equals(unsigned* __restrict__ meta,
                                                 float* __restrict__ laS, unsigned* __restrict__ laI,
                                                 const unsigned* __restrict__ lb) {
  __shared__ unsigned arr[LISTB_CAP];
  int t = threadIdx.x;
  unsigned E = meta[6];
  unsigned base = meta[7];
  unsigned cntB = meta[8];
  if (cntB > (unsigned)LISTB_CAP) cntB = LISTB_CAP;
  unsigned thr = (meta[0] << 20) | (meta[2] << 10) | meta[12];
  float thrF = __uint_as_float(thr);
  if (E == 0) return;
  // size to sort (power of two >= cntB), min 2
  int n2 = 2;
  while ((unsigned)n2 < cntB) n2 <<= 1;
  for (int i = t; i < n2; i += 1024) arr[i] = (i < (int)cntB) ? lb[i] : 0xFFFFFFFFu;
  __syncthreads();
  if (cntB != E) { // need lowest-index subset -> sort ascending
    for (int k = 2; k <= n2; k <<= 1) {
      for (int j = k >> 1; j > 0; j >>= 1) {
        for (int p = t; p < n2 / 2; p += 1024) {
          int i = ((p / j) * (2 * j)) + (p % j);
          int l = i + j;
          bool up = ((i & k) == 0);
          unsigned a = arr[i], b = arr[l];
          if ((a > b) == up) { arr[i] = b; arr[l] = a; }
        }
        __syncthreads();
      }
    }
  }
  for (int i = t; i < (int)E; i += 1024) {
    laS[base + i] = thrF;
    laI[base + i] = arr[i];
  }
}

// ---- bitonic sort 4096 keys descending: key = (score_bits<<32)|~idx ----
__global__ __launch_bounds__(1024) void k_sortkeys(const float* __restrict__ laS,
                                                   const unsigned* __restrict__ laI,
                                                   float* __restrict__ topS,
                                                   unsigned* __restrict__ topI) {
  __shared__ unsigned long long arr[PREK];
  int t = threadIdx.x;
  for (int i = t; i < PREK; i += 1024) {
    arr[i] = ((unsigned long long)__float_as_uint(laS[i]) << 32) |
             (unsigned long long)(~laI[i]);
  }
  __syncthreads();
  for (int k = 2; k <= PREK; k <<= 1) {
    for (int j = k >> 1; j > 0; j >>= 1) {
      for (int p = t; p < PREK / 2; p += 1024) {
        int i = ((p / j) * (2 * j)) + (p % j);
        int l = i + j;
        bool up = ((i & k) == 0); // descending
        unsigned long long a = arr[i], b = arr[l];
        if ((a < b) == up) { arr[i] = b; arr[l] = a; }
      }
      __syncthreads();
    }
  }
  for (int i = t; i < PREK; i += 1024) {
    unsigned long long key = arr[i];
    topS[i] = __uint_as_float((unsigned)(key >> 32));
    topI[i] = ~((unsigned)key);
  }
}

// ---- decode selected boxes ----
__global__ void k_decode(const float* __restrict__ cls, const float* __restrict__ box,
                         const float* __restrict__ dir, const float* __restrict__ anc,
                         const unsigned* __restrict__ topI,
                         float* __restrict__ tb, float* __restrict__ x1, float* __restrict__ x2,
                         float* __restrict__ y1, float* __restrict__ y2,
                         float* __restrict__ area, unsigned* __restrict__ label) {
  int i = blockIdx.x * blockDim.x + threadIdx.x;
  if (i >= PREK) return;
  size_t idx = (size_t)topI[i];
  const float* a = anc + idx * 7;
  const float* b = box + idx * 7;
  float xa = a[0], ya = a[1], za = a[2], dxa = a[3], dya = a[4], dza = a[5], ra = a[6];
  float xt = b[0], yt = b[1], zt = b[2], dxt = b[3], dyt = b[4], dzt = b[5], rt = b[6];
  za = za + dza * 0.5f;
  float diag = sqrtf(dxa * dxa + dya * dya);
  float xg = xt * diag + xa;
  float yg = yt * diag + ya;
  float zg = zt * dza + za;
  float dxg = (float)exp((double)dxt) * dxa;
  float dyg = (float)exp((double)dyt) * dya;
  float dzg = (float)exp((double)dzt) * dza;
  float rg = rt + ra;
  zg = zg - dzg * 0.5f;
  float d0 = dir[idx * 2], d1 = dir[idx * 2 + 1];
  float dl = (d1 > d0) ? 1.0f : 0.0f;
  float val = rg - DIR_OFFSET;
  val = val - floorf(val / PERIOD) * PERIOD;
  float rot = val + DIR_OFFSET + PERIOD * dl;
  float p0 = sigmoid_rn(cls[idx * 3 + 0]);
  float p1 = sigmoid_rn(cls[idx * 3 + 1]);
  float p2 = sigmoid_rn(cls[idx * 3 + 2]);
  unsigned lab = 1;
  float bestp = p0;
  if (p1 > bestp) { bestp = p1; lab = 2; }
  if (p2 > bestp) { bestp = p2; lab = 3; }
  tb[i * 7 + 0] = xg; tb[i * 7 + 1] = yg; tb[i * 7 + 2] = zg;
  tb[i * 7 + 3] = dxg; tb[i * 7 + 4] = dyg; tb[i * 7 + 5] = dzg;
  tb[i * 7 + 6] = rot;
  float X1 = xg - dxg * 0.5f, X2 = xg + dxg * 0.5f;
  float Y1 = yg - dyg * 0.5f, Y2 = yg + dyg * 0.5f;
  x1[i] = X1; x2[i] = X2; y1[i] = Y1; y2[i] = Y2;
  area[i] = (X2 - X1) * (Y2 - Y1);
  label[i] = lab;
}

// ---- pairwise IoU bitmask (bit set for j>i with iou>thresh) ----
__global__ void k_maskgen(const float* __restrict__ x1, const float* __restrict__ x2,
                          const float* __restrict__ y1, const float* __restrict__ y2,
                          const float* __restrict__ area,
                          unsigned long long* __restrict__ mask) {
  int g = blockIdx.x * blockDim.x + threadIdx.x;
  if (g >= PREK * 64) return;
  int i = g >> 6, w = g & 63;
  float X1 = x1[i], X2 = x2[i], Y1 = y1[i], Y2 = y2[i], A = area[i];
  unsigned long long m = 0;
  int j0 = w << 6;
  for (int b = 0; b < 64; ++b) {
    int j = j0 + b;
    if (j > i) {
      float ix = fminf(X2, x2[j]) - fmaxf(X1, x1[j]);
      ix = fmaxf(ix, 0.0f);
      float iy = fminf(Y2, y2[j]) - fmaxf(Y1, y1[j]);
      iy = fmaxf(iy, 0.0f);
      float inter = ix * iy;
      float iou = inter / (A + area[j] - inter + 1e-6f);
      if (iou > IOU_THRESH) m |= (1ull << b);
    }
  }
  mask[((size_t)i << 6) + w] = m;
}

// ---- single-wave greedy NMS reduction ----
__global__ void k_greedy(const float* __restrict__ topS,
                         const unsigned long long* __restrict__ mask,
                         unsigned long long* __restrict__ keepW) {
  int lane = threadIdx.x; // 64 threads = 1 wave
  unsigned long long validb = 0;
  for (int b = 0; b < 64; ++b)
    if (topS[(lane << 6) + b] > 0.0f) validb |= (1ull << b);
  unsigned long long removed = 0, keepb = 0;
  for (int i = 0; i < PREK; ++i) {
    int owner = i >> 6, bit = i & 63;
    unsigned remLo = __shfl((unsigned)(removed & 0xFFFFFFFFull), owner);
    unsigned remHi = __shfl((unsigned)(removed >> 32), owner);
    unsigned valLo = __shfl((unsigned)(validb & 0xFFFFFFFFull), owner);
    unsigned valHi = __shfl((unsigned)(validb >> 32), owner);
    unsigned long long remO = ((unsigned long long)remHi << 32) | remLo;
    unsigned long long valO = ((unsigned long long)valHi << 32) | valLo;
    bool keep_i = (((valO >> bit) & 1ull) != 0) && (((remO >> bit) & 1ull) == 0);
    if (keep_i) {
      if (lane == owner) keepb |= (1ull << bit);
      removed |= mask[((size_t)i << 6) + lane];
    }
  }
  keepW[lane] = keepb;
}

// ---- build 500 outputs: kept (index-asc) then non-kept (index-asc) ----
__global__ __launch_bounds__(512) void k_output(const float* __restrict__ topS,
                                                const float* __restrict__ tb,
                                                const unsigned* __restrict__ label,
                                                const unsigned long long* __restrict__ keepW,
                                                float* __restrict__ out) {
  __shared__ unsigned long long kw[64];
  __shared__ int part[512];
  __shared__ short keptList[PREK];
  __shared__ short nonKept[PREK];
  int t = threadIdx.x;
  if (t < 64) kw[t] = keepW[t];
  __syncthreads();
  int base = t * 8;
  int cnt = 0;
  for (int e = 0; e < 8; ++e) {
    int i = base + e;
    cnt += (int)((kw[i >> 6] >> (i & 63)) & 1ull);
  }
  part[t] = cnt;
  __syncthreads();
  for (int off = 1; off < 512; off <<= 1) {
    int v = part[t];
    int add = (t >= off) ? part[t - off] : 0;
    __syncthreads();
    part[t] = v + add;
    __syncthreads();
  }
  int kbase = part[t] - cnt;
  int nbase = base - kbase;
  for (int e = 0; e < 8; ++e) {
    int i = base + e;
    bool kp = ((kw[i >> 6] >> (i & 63)) & 1ull) != 0;
    if (kp) keptList[kbase++] = (short)i;
    else nonKept[nbase++] = (short)i;
  }
  __syncthreads();
  int keptCount = part[511];
  for (int k = t; k < POSTK; k += 512) {
    int i;
    float s;
    if (k < keptCount) { i = keptList[k]; s = topS[i]; }
    else { i = nonKept[k - keptCount]; s = 0.0f; }
    for (int c = 0; c < 7; ++c) out[k * 8 + c] = tb[i * 7 + c];
    out[k * 8 + 7] = s;
    out[POSTK * 8 + k] = (float)label[i];
  }
}

extern "C" void kernel_launch(void* const* d_in, const int* in_sizes, int n_in,
                              void* d_out, int out_size, void* d_ws, size_t ws_size,
                              hipStream_t stream) {
  const float* cls = (const float*)d_in[0];
  const float* box = (const float*)d_in[1];
  const float* dir = (const float*)d_in[2];
  const float* anc = (const float*)d_in[3];
  float* out = (float*)d_out;
  char* ws = (char*)d_ws;
  if (ws_size < WS_NEED) return;

  float* scores = (float*)(ws + oScores);
  unsigned* hist12 = (unsigned*)(ws + oHist12);
  unsigned* histA = (unsigned*)(ws + oHistA);
  unsigned* histB = (unsigned*)(ws + oHistB);
  unsigned* meta = (unsigned*)(ws + oMeta);
  float* laS = (float*)(ws + oListAS);
  unsigned* laI = (unsigned*)(ws + oListAI);
  unsigned* lb = (unsigned*)(ws + oListB);
  float* topS = (float*)(ws + oTopS);
  unsigned* topI = (unsigned*)(ws + oTopI);
  float* tb = (float*)(ws + oTB);
  float* x1 = (float*)(ws + oX1);
  float* x2 = (float*)(ws + oX2);
  float* y1 = (float*)(ws + oY1);
  float* y2 = (float*)(ws + oY2);
  float* area = (float*)(ws + oArea);
  unsigned* label = (unsigned*)(ws + oLabel);
  unsigned long long* keepW = (unsigned long long*)(ws + oKeepW);
  unsigned long long* mask = (unsigned long long*)(ws + oMask);

  // zero hists + meta (everything else is fully overwritten before read)
  hipMemsetAsync(ws + oHist12, 0, (oListAS - oHist12), stream);

  k_scores<<<1024, 256, 0, stream>>>(cls, scores, hist12);
  k_scan<<<1, 256, 0, stream>>>(hist12, meta, 4096, -1, 0, 1, 10);
  k_hist_refine<<<1024, 256, 0, stream>>>(scores, histA, meta, 0);
  k_scan<<<1, 256, 0, stream>>>(histA, meta, 1024, 1, 2, 3, 11);
  k_hist_refine<<<1024, 256, 0, stream>>>(scores, histB, meta, 1);
  k_scan<<<1, 256, 0, stream>>>(histB, meta, 1024, 3, 12, 5, 6);
  k_compact<<<1024, 256, 0, stream>>>(scores, meta, laS, laI, lb);
  k_equals<<<1, 1024, 0, stream>>>(meta, laS, laI, lb);
  k_sortkeys<<<1, 1024, 0, stream>>>(laS, laI, topS, topI);
  k_decode<<<PREK / 256, 256, 0, stream>>>(cls, box, dir, anc, topI, tb, x1, x2, y1, y2, area, label);
  k_maskgen<<<PREK * 64 / 256, 256, 0, stream>>>(x1, x2, y1, y2, area, mask);
  k_greedy<<<1, 64, 0, stream>>>(topS, mask, keepW);
  k_output<<<1, 512, 0, stream>>>(topS, tb, label, keepW, out);
}

// Round 2
// 407.939 us; speedup vs baseline: 2.3896x; 2.3896x over previous
//
#include <hip/hip_runtime.h>
#include <math.h>

namespace {
constexpr int H = 512, W = 512, NUM_ANCH = 6;
constexpr int N = H * W * NUM_ANCH;          // 1572864
constexpr int PREK = 4096;
constexpr int POSTK = 500;
constexpr float SCORE_THRESH = 0.1f;
constexpr float IOU_THRESH = 0.01f;
constexpr float DIR_OFFSET = 0.78539f;
constexpr float PERIOD = 3.14159265358979323846f; // f32(pi)
constexpr int LISTB_CAP = 8192;

// ---- workspace byte offsets ----
constexpr size_t oScores = 0;                                  // N f32
constexpr size_t oHist12 = (size_t)N * 4;                      // 4096 u32
constexpr size_t oHistA  = oHist12 + 4096 * 4;                 // 1024 u32
constexpr size_t oHistB  = oHistA + 1024 * 4;                  // 1024 u32
constexpr size_t oMeta   = oHistB + 1024 * 4;                  // 64 u32
constexpr size_t oListAS = oMeta + 64 * 4;                     // PREK f32
constexpr size_t oListAI = oListAS + PREK * 4;                 // PREK u32
constexpr size_t oListB  = oListAI + PREK * 4;                 // LISTB_CAP u32
constexpr size_t oTopS   = oListB + (size_t)LISTB_CAP * 4;     // PREK f32
constexpr size_t oTopI   = oTopS + PREK * 4;                   // PREK u32
constexpr size_t oTB     = oTopI + PREK * 4;                   // PREK*7 f32
constexpr size_t oB4     = oTB + (size_t)PREK * 7 * 4;         // PREK float4 (x1,y1,x2,y2)
constexpr size_t oLabel  = oB4 + (size_t)PREK * 16;            // PREK u32
constexpr size_t oKeepW  = oLabel + PREK * 4;                  // 64 u64
constexpr size_t oMask   = oKeepW + 64 * 8;                    // PREK*64 u64
constexpr size_t WS_NEED = oMask + (size_t)PREK * 64 * 8;
// meta slots: 0:T1 1:G1 2:T2 3:G2 12:T3 5:G 6:E 7:cntA 8:cntB
}

__device__ __forceinline__ float sigmoid_rn(float x) {
  // correctly-rounded-to-f32 sigmoid via double
  return (float)(1.0 / (1.0 + exp(-(double)x)));
}

__device__ __forceinline__ unsigned long long shfl64(unsigned long long v, int src) {
  unsigned lo = __shfl((unsigned)(v & 0xFFFFFFFFull), src);
  unsigned hi = __shfl((unsigned)(v >> 32), src);
  return ((unsigned long long)hi << 32) | lo;
}

// ---- 1: per-anchor score + 12-bit histogram ----
__global__ void k_scores(const float* __restrict__ cls, float* __restrict__ scores,
                         unsigned* __restrict__ hist12) {
  __shared__ unsigned h[4096];
  for (int t = threadIdx.x; t < 4096; t += blockDim.x) h[t] = 0;
  __syncthreads();
  int stride = gridDim.x * blockDim.x;
  for (int n = blockIdx.x * blockDim.x + threadIdx.x; n < N; n += stride) {
    float l0 = cls[n * 3 + 0];
    float l1 = cls[n * 3 + 1];
    float l2 = cls[n * 3 + 2];
    float m = fmaxf(l0, fmaxf(l1, l2));
    float s = sigmoid_rn(m);               // max(sigmoid)=sigmoid(max), monotone+crn
    s = (s >= SCORE_THRESH) ? s : 0.0f;
    scores[n] = s;
    atomicAdd(&h[__float_as_uint(s) >> 20], 1u);
  }
  __syncthreads();
  for (int t = threadIdx.x; t < 4096; t += blockDim.x) {
    unsigned v = h[t];
    if (v) atomicAdd(&hist12[t], v);
  }
}

// ---- generic scan: find bin where cumulative-from-top crosses R ----
__global__ void k_scan(const unsigned* __restrict__ hist, unsigned* __restrict__ meta,
                       int nbins, int prevGslot, int outBin, int outG, int outE) {
  __shared__ unsigned part[256];
  int t = threadIdx.x;
  int chunk = nbins >> 8;
  unsigned prevG = (prevGslot >= 0) ? meta[prevGslot] : 0u;
  unsigned R = (unsigned)PREK - prevG;
  unsigned s = 0;
  for (int c = 0; c < chunk; ++c) s += hist[t * chunk + c];
  part[t] = s;
  __syncthreads();
  for (int off = 1; off < 256; off <<= 1) {
    unsigned v = part[t];
    unsigned add = (t + off < 256) ? part[t + off] : 0u;
    __syncthreads();
    part[t] = v + add;
    __syncthreads();
  }
  unsigned cum = (t == 255) ? 0u : part[t + 1];
  for (int c = chunk - 1; c >= 0; --c) {
    unsigned hv = hist[t * chunk + c];
    unsigned above = cum;
    cum += hv;
    if (cum >= R && above < R) {
      meta[outBin] = (unsigned)(t * chunk + c);
      meta[outG] = prevG + above;
      meta[outE] = R - above;
    }
  }
}

// ---- refine histograms (mode 0: bits[19:10] within top-12 bin; mode 1: bits[9:0]) ----
__global__ void k_hist_refine(const float* __restrict__ scores, unsigned* __restrict__ hist,
                              const unsigned* __restrict__ meta, int mode) {
  __shared__ unsigned h[1024];
  for (int t = threadIdx.x; t < 1024; t += blockDim.x) h[t] = 0;
  __syncthreads();
  unsigned m0 = meta[0], m2 = meta[2];
  unsigned pref22 = (m0 << 10) | m2;
  int stride = gridDim.x * blockDim.x;
  for (int n = blockIdx.x * blockDim.x + threadIdx.x; n < N; n += stride) {
    unsigned bits = __float_as_uint(scores[n]);
    if (mode == 0) {
      if ((bits >> 20) == m0) atomicAdd(&h[(bits >> 10) & 1023u], 1u);
    } else {
      if ((bits >> 10) == pref22) atomicAdd(&h[bits & 1023u], 1u);
    }
  }
  __syncthreads();
  for (int t = threadIdx.x; t < 1024; t += blockDim.x) {
    unsigned v = h[t];
    if (v) atomicAdd(&hist[t], v);
  }
}

// ---- compact > thr and == thr ----
__global__ void k_compact(const float* __restrict__ scores, unsigned* __restrict__ meta,
                          float* __restrict__ laS, unsigned* __restrict__ laI,
                          unsigned* __restrict__ lb) {
  unsigned thr = (meta[0] << 20) | (meta[2] << 10) | meta[12];
  int stride = gridDim.x * blockDim.x;
  for (int n = blockIdx.x * blockDim.x + threadIdx.x; n < N; n += stride) {
    float sv = scores[n];
    unsigned bits = __float_as_uint(sv);
    if (bits > thr) {
      unsigned pos = atomicAdd(&meta[7], 1u);
      if (pos < (unsigned)PREK) { laS[pos] = sv; laI[pos] = (unsigned)n; }
    } else if (bits == thr) {
      unsigned pos = atomicAdd(&meta[8], 1u);
      if (pos < (unsigned)LISTB_CAP) lb[pos] = (unsigned)n;
    }
  }
}

// ---- pick lowest-index ties, append to listA ----
__global__ __launch_bounds__(1024) void k_equals(unsigned* __restrict__ meta,
                                                 float* __restrict__ laS, unsigned* __restrict__ laI,
                                                 const unsigned* __restrict__ lb) {
  __shared__ unsigned arr[LISTB_CAP];
  int t = threadIdx.x;
  unsigned E = meta[6];
  unsigned base = meta[7];
  unsigned cntB = meta[8];
  if (cntB > (unsigned)LISTB_CAP) cntB = LISTB_CAP;
  unsigned thr = (meta[0] << 20) | (meta[2] << 10) | meta[12];
  float thrF = __uint_as_float(thr);
  if (E == 0) return;
  int n2 = 2;
  while ((unsigned)n2 < cntB) n2 <<= 1;
  for (int i = t; i < n2; i += 1024) arr[i] = (i < (int)cntB) ? lb[i] : 0xFFFFFFFFu;
  __syncthreads();
  if (cntB != E) { // need lowest-index subset -> sort ascending
    for (int k = 2; k <= n2; k <<= 1) {
      for (int j = k >> 1; j > 0; j >>= 1) {
        for (int p = t; p < n2 / 2; p += 1024) {
          int i = ((p / j) * (2 * j)) + (p % j);
          int l = i + j;
          bool up = ((i & k) == 0);
          unsigned a = arr[i], b = arr[l];
          if ((a > b) == up) { arr[i] = b; arr[l] = a; }
        }
        __syncthreads();
      }
    }
  }
  for (int i = t; i < (int)E; i += 1024) {
    laS[base + i] = thrF;
    laI[base + i] = arr[i];
  }
}

// ---- bitonic sort 4096 keys descending: key = (score_bits<<32)|~idx ----
__global__ __launch_bounds__(1024) void k_sortkeys(const float* __restrict__ laS,
                                                   const unsigned* __restrict__ laI,
                                                   float* __restrict__ topS,
                                                   unsigned* __restrict__ topI) {
  __shared__ unsigned long long arr[PREK];
  int t = threadIdx.x;
  for (int i = t; i < PREK; i += 1024) {
    arr[i] = ((unsigned long long)__float_as_uint(laS[i]) << 32) |
             (unsigned long long)(~laI[i]);
  }
  __syncthreads();
  for (int k = 2; k <= PREK; k <<= 1) {
    for (int j = k >> 1; j > 0; j >>= 1) {
      for (int p = t; p < PREK / 2; p += 1024) {
        int i = ((p / j) * (2 * j)) + (p % j);
        int l = i + j;
        bool up = ((i & k) == 0); // descending
        unsigned long long a = arr[i], b = arr[l];
        if ((a < b) == up) { arr[i] = b; arr[l] = a; }
      }
      __syncthreads();
    }
  }
  for (int i = t; i < PREK; i += 1024) {
    unsigned long long key = arr[i];
    topS[i] = __uint_as_float((unsigned)(key >> 32));
    topI[i] = ~((unsigned)key);
  }
}

// ---- decode selected boxes ----
__global__ void k_decode(const float* __restrict__ cls, const float* __restrict__ box,
                         const float* __restrict__ dir, const float* __restrict__ anc,
                         const unsigned* __restrict__ topI,
                         float* __restrict__ tb, float4* __restrict__ b4,
                         unsigned* __restrict__ label) {
  int i = blockIdx.x * blockDim.x + threadIdx.x;
  if (i >= PREK) return;
  size_t idx = (size_t)topI[i];
  const float* a = anc + idx * 7;
  const float* b = box + idx * 7;
  float xa = a[0], ya = a[1], za = a[2], dxa = a[3], dya = a[4], dza = a[5], ra = a[6];
  float xt = b[0], yt = b[1], zt = b[2], dxt = b[3], dyt = b[4], dzt = b[5], rt = b[6];
  za = za + dza * 0.5f;
  float diag = sqrtf(dxa * dxa + dya * dya);
  float xg = xt * diag + xa;
  float yg = yt * diag + ya;
  float zg = zt * dza + za;
  float dxg = (float)exp((double)dxt) * dxa;
  float dyg = (float)exp((double)dyt) * dya;
  float dzg = (float)exp((double)dzt) * dza;
  float rg = rt + ra;
  zg = zg - dzg * 0.5f;
  float d0 = dir[idx * 2], d1 = dir[idx * 2 + 1];
  float dl = (d1 > d0) ? 1.0f : 0.0f;
  float val = rg - DIR_OFFSET;
  val = val - floorf(val / PERIOD) * PERIOD;
  float rot = val + DIR_OFFSET + PERIOD * dl;
  // argmax(sigmoid(l)) == argmax(l) (monotone), first-max tie semantics preserved
  float l0 = cls[idx * 3 + 0];
  float l1 = cls[idx * 3 + 1];
  float l2 = cls[idx * 3 + 2];
  unsigned lab = 1;
  float bestl = l0;
  if (l1 > bestl) { bestl = l1; lab = 2; }
  if (l2 > bestl) { bestl = l2; lab = 3; }
  tb[i * 7 + 0] = xg; tb[i * 7 + 1] = yg; tb[i * 7 + 2] = zg;
  tb[i * 7 + 3] = dxg; tb[i * 7 + 4] = dyg; tb[i * 7 + 5] = dzg;
  tb[i * 7 + 6] = rot;
  float X1 = xg - dxg * 0.5f, X2 = xg + dxg * 0.5f;
  float Y1 = yg - dyg * 0.5f, Y2 = yg + dyg * 0.5f;
  b4[i] = make_float4(X1, Y1, X2, Y2);
  label[i] = lab;
}

// ---- pairwise IoU bitmask, LDS-staged, ballot-per-word ----
// grid MUST be 256 blocks x 256 threads; block b handles rows {b, b+256, ..., b+3840}
__global__ __launch_bounds__(256) void k_maskgen(const float4* __restrict__ b4,
                                                 unsigned long long* __restrict__ mask) {
  __shared__ float4 sb[PREK];   // 64 KB
  int t = threadIdx.x;
  for (int i = t; i < PREK; i += 256) sb[i] = b4[i];
  __syncthreads();
  int lane = t & 63, wv = t >> 6;
  for (int k = wv; k < 16; k += 4) {
    int r = blockIdx.x + (k << 8);
    float4 bi = sb[r];
    float A = (bi.z - bi.x) * (bi.w - bi.y);
    unsigned long long myword = 0;
    int w0 = r >> 6;
    for (int w = w0; w < 64; ++w) {
      int j = (w << 6) + lane;
      float4 bj = sb[j];
      float ix = fminf(bi.z, bj.z) - fmaxf(bi.x, bj.x); ix = fmaxf(ix, 0.0f);
      float iy = fminf(bi.w, bj.w) - fmaxf(bi.y, bj.y); iy = fmaxf(iy, 0.0f);
      float inter = ix * iy;
      float Aj = (bj.z - bj.x) * (bj.w - bj.y);   // identical expr to decode's area
      float iou = inter / (A + Aj - inter + 1e-6f);
      unsigned long long word = __ballot(j > r && iou > IOU_THRESH);
      if (lane == w) myword = word;
    }
    mask[((size_t)r << 6) + lane] = myword;
  }
}

// ---- single-wave greedy NMS, chunked bit-skip ----
__global__ __launch_bounds__(64) void k_greedy(const float* __restrict__ topS,
                                               const unsigned long long* __restrict__ mask,
                                               unsigned long long* __restrict__ keepW) {
  int lane = threadIdx.x;
  // validb: lane l holds valid bits for boxes [l*64, l*64+64) via ballot
  unsigned long long validb = 0;
  for (int w = 0; w < 64; ++w) {
    unsigned long long word = __ballot(topS[(w << 6) + lane] > 0.0f);
    if (lane == w) validb = word;
  }
  unsigned long long removed_l = 0;  // removed bits for lane's own chunk
  unsigned long long keep_l = 0;
  // prefetch intra word for chunk 0: lane b holds mask[row b][word 0]
  unsigned long long m_intra = mask[((size_t)lane << 6) + 0];
  for (int c = 0; c < 64; ++c) {
    unsigned long long remC = shfl64(removed_l, c);
    unsigned long long valC = shfl64(validb, c);
    unsigned long long m_cur = m_intra;
    if (c + 1 < 64)
      m_intra = mask[((size_t)(((c + 1) << 6) + lane) << 6) + (c + 1)];
    unsigned long long pending = valC & ~remC;
    unsigned long long kept = 0;
    while (pending) {
      int b = __ffsll(pending) - 1;
      kept |= (1ull << b);
      unsigned long long mb = shfl64(m_cur, b);   // intra-chunk suppression row
      pending &= (pending - 1);                   // clear bit b
      pending &= ~mb;                             // drop suppressed
    }
    // apply full rows of kept boxes to own removed word (batched, 8 loads in flight)
    unsigned long long kw = kept;
    while (kw) {
      unsigned long long v0 = 0, v1 = 0, v2 = 0, v3 = 0, v4 = 0, v5 = 0, v6 = 0, v7 = 0;
      int b;
      if (kw) { b = __ffsll(kw) - 1; kw &= kw - 1; v0 = mask[((size_t)((c << 6) + b) << 6) + lane]; }
      if (kw) { b = __ffsll(kw) - 1; kw &= kw - 1; v1 = mask[((size_t)((c << 6) + b) << 6) + lane]; }
      if (kw) { b = __ffsll(kw) - 1; kw &= kw - 1; v2 = mask[((size_t)((c << 6) + b) << 6) + lane]; }
      if (kw) { b = __ffsll(kw) - 1; kw &= kw - 1; v3 = mask[((size_t)((c << 6) + b) << 6) + lane]; }
      if (kw) { b = __ffsll(kw) - 1; kw &= kw - 1; v4 = mask[((size_t)((c << 6) + b) << 6) + lane]; }
      if (kw) { b = __ffsll(kw) - 1; kw &= kw - 1; v5 = mask[((size_t)((c << 6) + b) << 6) + lane]; }
      if (kw) { b = __ffsll(kw) - 1; kw &= kw - 1; v6 = mask[((size_t)((c << 6) + b) << 6) + lane]; }
      if (kw) { b = __ffsll(kw) - 1; kw &= kw - 1; v7 = mask[((size_t)((c << 6) + b) << 6) + lane]; }
      removed_l |= (v0 | v1) | (v2 | v3) | ((v4 | v5) | (v6 | v7));
    }
    if (lane == c) keep_l = kept;
  }
  keepW[lane] = keep_l;
}

// ---- build 500 outputs: kept (index-asc) then non-kept (index-asc) ----
__global__ __launch_bounds__(512) void k_output(const float* __restrict__ topS,
                                                const float* __restrict__ tb,
                                                const unsigned* __restrict__ label,
                                                const unsigned long long* __restrict__ keepW,
                                                float* __restrict__ out) {
  __shared__ unsigned long long kw[64];
  __shared__ int part[512];
  __shared__ short keptList[PREK];
  __shared__ short nonKept[PREK];
  int t = threadIdx.x;
  if (t < 64) kw[t] = keepW[t];
  __syncthreads();
  int base = t * 8;
  int cnt = 0;
  for (int e = 0; e < 8; ++e) {
    int i = base + e;
    cnt += (int)((kw[i >> 6] >> (i & 63)) & 1ull);
  }
  part[t] = cnt;
  __syncthreads();
  for (int off = 1; off < 512; off <<= 1) {
    int v = part[t];
    int add = (t >= off) ? part[t - off] : 0;
    __syncthreads();
    part[t] = v + add;
    __syncthreads();
  }
  int kbase = part[t] - cnt;
  int nbase = base - kbase;
  for (int e = 0; e < 8; ++e) {
    int i = base + e;
    bool kp = ((kw[i >> 6] >> (i & 63)) & 1ull) != 0;
    if (kp) keptList[kbase++] = (short)i;
    else nonKept[nbase++] = (short)i;
  }
  __syncthreads();
  int keptCount = part[511];
  for (int k = t; k < POSTK; k += 512) {
    int i;
    float s;
    if (k < keptCount) { i = keptList[k]; s = topS[i]; }
    else { i = nonKept[k - keptCount]; s = 0.0f; }
    for (int c = 0; c < 7; ++c) out[k * 8 + c] = tb[i * 7 + c];
    out[k * 8 + 7] = s;
    out[POSTK * 8 + k] = (float)label[i];
  }
}

extern "C" void kernel_launch(void* const* d_in, const int* in_sizes, int n_in,
                              void* d_out, int out_size, void* d_ws, size_t ws_size,
                              hipStream_t stream) {
  const float* cls = (const float*)d_in[0];
  const float* box = (const float*)d_in[1];
  const float* dir = (const float*)d_in[2];
  const float* anc = (const float*)d_in[3];
  float* out = (float*)d_out;
  char* ws = (char*)d_ws;
  if (ws_size < WS_NEED) return;

  float* scores = (float*)(ws + oScores);
  unsigned* hist12 = (unsigned*)(ws + oHist12);
  unsigned* histA = (unsigned*)(ws + oHistA);
  unsigned* histB = (unsigned*)(ws + oHistB);
  unsigned* meta = (unsigned*)(ws + oMeta);
  float* laS = (float*)(ws + oListAS);
  unsigned* laI = (unsigned*)(ws + oListAI);
  unsigned* lb = (unsigned*)(ws + oListB);
  float* topS = (float*)(ws + oTopS);
  unsigned* topI = (unsigned*)(ws + oTopI);
  float* tb = (float*)(ws + oTB);
  float4* b4 = (float4*)(ws + oB4);
  unsigned* label = (unsigned*)(ws + oLabel);
  unsigned long long* keepW = (unsigned long long*)(ws + oKeepW);
  unsigned long long* mask = (unsigned long long*)(ws + oMask);

  // zero hists + meta (everything else fully overwritten before read)
  hipMemsetAsync(ws + oHist12, 0, (oListAS - oHist12), stream);

  k_scores<<<1024, 256, 0, stream>>>(cls, scores, hist12);
  k_scan<<<1, 256, 0, stream>>>(hist12, meta, 4096, -1, 0, 1, 10);
  k_hist_refine<<<1024, 256, 0, stream>>>(scores, histA, meta, 0);
  k_scan<<<1, 256, 0, stream>>>(histA, meta, 1024, 1, 2, 3, 11);
  k_hist_refine<<<1024, 256, 0, stream>>>(scores, histB, meta, 1);
  k_scan<<<1, 256, 0, stream>>>(histB, meta, 1024, 3, 12, 5, 6);
  k_compact<<<1024, 256, 0, stream>>>(scores, meta, laS, laI, lb);
  k_equals<<<1, 1024, 0, stream>>>(meta, laS, laI, lb);
  k_sortkeys<<<1, 1024, 0, stream>>>(laS, laI, topS, topI);
  k_decode<<<PREK / 256, 256, 0, stream>>>(cls, box, dir, anc, topI, tb, b4, label);
  k_maskgen<<<256, 256, 0, stream>>>(b4, mask);
  k_greedy<<<1, 64, 0, stream>>>(topS, mask, keepW);
  k_output<<<1, 512, 0, stream>>>(topS, tb, label, keepW, out);
}

// Round 3
// 351.172 us; speedup vs baseline: 2.7759x; 1.1616x over previous
//
#include <hip/hip_runtime.h>
#include <math.h>

namespace {
constexpr int H = 512, W = 512, NUM_ANCH = 6;
constexpr int N = H * W * NUM_ANCH;          // 1572864
constexpr int NG = N / 4;                    // 393216 groups of 4 anchors
constexpr int PREK = 4096;
constexpr int POSTK = 500;
constexpr float SCORE_THRESH = 0.1f;
constexpr float IOU_THRESH = 0.01f;
constexpr float DIR_OFFSET = 0.78539f;
constexpr float PERIOD = 3.14159265358979323846f; // f32(pi)
constexpr int LISTB_CAP = 8192;

// ---- workspace byte offsets ----
constexpr size_t oScores = 0;                                  // N f32
constexpr size_t oHist12 = (size_t)N * 4;                      // 4096 u32
constexpr size_t oHistA  = oHist12 + 4096 * 4;                 // 1024 u32
constexpr size_t oHistB  = oHistA + 1024 * 4;                  // 1024 u32
constexpr size_t oMeta   = oHistB + 1024 * 4;                  // 64 u32
constexpr size_t oListAS = oMeta + 64 * 4;                     // PREK f32
constexpr size_t oListAI = oListAS + PREK * 4;                 // PREK u32
constexpr size_t oListB  = oListAI + PREK * 4;                 // LISTB_CAP u32
constexpr size_t oTopS   = oListB + (size_t)LISTB_CAP * 4;     // PREK f32
constexpr size_t oTopI   = oTopS + PREK * 4;                   // PREK u32
constexpr size_t oTB     = oTopI + PREK * 4;                   // PREK*7 f32
constexpr size_t oB4     = oTB + (size_t)PREK * 7 * 4;         // PREK float4
constexpr size_t oLabel  = oB4 + (size_t)PREK * 16;            // PREK u32
constexpr size_t oValidW = oLabel + PREK * 4;                  // 64 u64
constexpr size_t oMask   = oValidW + 64 * 8;                   // PREK*64 u64
constexpr size_t WS_NEED = oMask + (size_t)PREK * 64 * 8;
// meta slots: 0:T1 1:G1 2:T2 3:G2 12:T3 5:G 6:E 7:cntA 8:cntB
}

__device__ __forceinline__ float sigmoid_rn(float x) {
  // correctly-rounded-to-f32 sigmoid via double (matches np f64 reference)
  return (float)(1.0 / (1.0 + exp(-(double)x)));
}

__device__ __forceinline__ unsigned long long rdl64(unsigned long long v, int src) {
  unsigned lo = (unsigned)__builtin_amdgcn_readlane((int)(unsigned)v, src);
  unsigned hi = (unsigned)__builtin_amdgcn_readlane((int)(unsigned)(v >> 32), src);
  return ((unsigned long long)hi << 32) | lo;
}

// ---- 1: per-anchor score + 12-bit histogram (4 anchors/thread via float4) ----
__global__ __launch_bounds__(256) void k_scores(const float4* __restrict__ cls4,
                                                float4* __restrict__ scores4,
                                                unsigned* __restrict__ hist12) {
  __shared__ unsigned h[4096];
  for (int t = threadIdx.x; t < 4096; t += 256) h[t] = 0;
  __syncthreads();
  int g = blockIdx.x * 256 + threadIdx.x;      // g < NG (grid sized exactly)
  float4 a = cls4[(size_t)g * 3 + 0];
  float4 b = cls4[(size_t)g * 3 + 1];
  float4 c = cls4[(size_t)g * 3 + 2];
  float m0 = fmaxf(a.x, fmaxf(a.y, a.z));
  float m1 = fmaxf(a.w, fmaxf(b.x, b.y));
  float m2 = fmaxf(b.z, fmaxf(b.w, c.x));
  float m3 = fmaxf(c.y, fmaxf(c.z, c.w));
  float s0 = sigmoid_rn(m0); s0 = (s0 >= SCORE_THRESH) ? s0 : 0.0f;
  float s1 = sigmoid_rn(m1); s1 = (s1 >= SCORE_THRESH) ? s1 : 0.0f;
  float s2 = sigmoid_rn(m2); s2 = (s2 >= SCORE_THRESH) ? s2 : 0.0f;
  float s3 = sigmoid_rn(m3); s3 = (s3 >= SCORE_THRESH) ? s3 : 0.0f;
  scores4[g] = make_float4(s0, s1, s2, s3);
  atomicAdd(&h[__float_as_uint(s0) >> 20], 1u);
  atomicAdd(&h[__float_as_uint(s1) >> 20], 1u);
  atomicAdd(&h[__float_as_uint(s2) >> 20], 1u);
  atomicAdd(&h[__float_as_uint(s3) >> 20], 1u);
  __syncthreads();
  for (int t = threadIdx.x; t < 4096; t += 256) {
    unsigned v = h[t];
    if (v) atomicAdd(&hist12[t], v);
  }
}

// ---- generic scan: find bin where cumulative-from-top crosses R ----
__global__ void k_scan(const unsigned* __restrict__ hist, unsigned* __restrict__ meta,
                       int nbins, int prevGslot, int outBin, int outG, int outE) {
  __shared__ unsigned part[256];
  int t = threadIdx.x;
  int chunk = nbins >> 8;
  unsigned prevG = (prevGslot >= 0) ? meta[prevGslot] : 0u;
  unsigned R = (unsigned)PREK - prevG;
  unsigned s = 0;
  for (int c = 0; c < chunk; ++c) s += hist[t * chunk + c];
  part[t] = s;
  __syncthreads();
  for (int off = 1; off < 256; off <<= 1) {
    unsigned v = part[t];
    unsigned add = (t + off < 256) ? part[t + off] : 0u;
    __syncthreads();
    part[t] = v + add;
    __syncthreads();
  }
  unsigned cum = (t == 255) ? 0u : part[t + 1];
  for (int c = chunk - 1; c >= 0; --c) {
    unsigned hv = hist[t * chunk + c];
    unsigned above = cum;
    cum += hv;
    if (cum >= R && above < R) {
      meta[outBin] = (unsigned)(t * chunk + c);
      meta[outG] = prevG + above;
      meta[outE] = R - above;
    }
  }
}

// ---- refine histograms, 4-wide ----
__global__ __launch_bounds__(256) void k_refine(const float4* __restrict__ scores4,
                                                unsigned* __restrict__ hist,
                                                const unsigned* __restrict__ meta, int mode) {
  __shared__ unsigned h[1024];
  for (int t = threadIdx.x; t < 1024; t += 256) h[t] = 0;
  __syncthreads();
  unsigned m0 = meta[0];
  unsigned pref22 = (m0 << 10) | meta[2];
  int g = blockIdx.x * 256 + threadIdx.x;
  float4 s = scores4[g];
  unsigned bb[4] = {__float_as_uint(s.x), __float_as_uint(s.y),
                    __float_as_uint(s.z), __float_as_uint(s.w)};
#pragma unroll
  for (int k = 0; k < 4; ++k) {
    unsigned bits = bb[k];
    if (mode == 0) {
      if ((bits >> 20) == m0) atomicAdd(&h[(bits >> 10) & 1023u], 1u);
    } else {
      if ((bits >> 10) == pref22) atomicAdd(&h[bits & 1023u], 1u);
    }
  }
  __syncthreads();
  for (int t = threadIdx.x; t < 1024; t += 256) {
    unsigned v = h[t];
    if (v) atomicAdd(&hist[t], v);
  }
}

// ---- compact > thr and == thr, 4-wide ----
__global__ __launch_bounds__(256) void k_compact(const float4* __restrict__ scores4,
                                                 unsigned* __restrict__ meta,
                                                 float* __restrict__ laS, unsigned* __restrict__ laI,
                                                 unsigned* __restrict__ lb) {
  unsigned thr = (meta[0] << 20) | (meta[2] << 10) | meta[12];
  int g = blockIdx.x * 256 + threadIdx.x;
  float4 s = scores4[g];
  float sv[4] = {s.x, s.y, s.z, s.w};
#pragma unroll
  for (int k = 0; k < 4; ++k) {
    unsigned bits = __float_as_uint(sv[k]);
    int n = g * 4 + k;
    if (bits > thr) {
      unsigned pos = atomicAdd(&meta[7], 1u);
      if (pos < (unsigned)PREK) { laS[pos] = sv[k]; laI[pos] = (unsigned)n; }
    } else if (bits == thr) {
      unsigned pos = atomicAdd(&meta[8], 1u);
      if (pos < (unsigned)LISTB_CAP) lb[pos] = (unsigned)n;
    }
  }
}

// ---- fused: tie-resolution + bitonic sort + validW emission ----
__global__ __launch_bounds__(1024) void k_select(const unsigned* __restrict__ meta,
                                                 const float* __restrict__ laS,
                                                 const unsigned* __restrict__ laI,
                                                 const unsigned* __restrict__ lb,
                                                 float* __restrict__ topS,
                                                 unsigned* __restrict__ topI,
                                                 unsigned long long* __restrict__ validW) {
  __shared__ unsigned arrB[LISTB_CAP];            // 32 KB
  __shared__ unsigned long long arr[PREK];        // 32 KB
  int t = threadIdx.x;
  unsigned E = meta[6];
  unsigned G = meta[7];                           // count of strictly-greater
  unsigned cntB = meta[8];
  if (cntB > (unsigned)LISTB_CAP) cntB = LISTB_CAP;
  unsigned thr = (meta[0] << 20) | (meta[2] << 10) | meta[12];

  // phase 1: pick E lowest-index ties, write keys into arr[G..G+E)
  if (E != 0) {                                   // uniform branch
    int n2 = 2;
    while ((unsigned)n2 < cntB) n2 <<= 1;
    for (int i = t; i < n2; i += 1024) arrB[i] = (i < (int)cntB) ? lb[i] : 0xFFFFFFFFu;
    __syncthreads();
    if (cntB != E) {                              // uniform
      for (int k = 2; k <= n2; k <<= 1) {
        for (int j = k >> 1; j > 0; j >>= 1) {
          for (int p = t; p < n2 / 2; p += 1024) {
            int i = ((p / j) * (2 * j)) + (p % j);
            int l = i + j;
            bool up = ((i & k) == 0);
            unsigned a = arrB[i], b = arrB[l];
            if ((a > b) == up) { arrB[i] = b; arrB[l] = a; }
          }
          __syncthreads();
        }
      }
    }
    for (int i = t; i < (int)E; i += 1024)
      arr[G + i] = ((unsigned long long)thr << 32) | (unsigned long long)(~arrB[i]);
  }
  __syncthreads();
  // phase 2: load strictly-greater entries, sort all PREK descending
  for (int i = t; i < PREK; i += 1024)
    if (i < (int)G)
      arr[i] = ((unsigned long long)__float_as_uint(laS[i]) << 32) |
               (unsigned long long)(~laI[i]);
  __syncthreads();
  for (int k = 2; k <= PREK; k <<= 1) {
    for (int j = k >> 1; j > 0; j >>= 1) {
      for (int p = t; p < PREK / 2; p += 1024) {
        int i = ((p / j) * (2 * j)) + (p % j);
        int l = i + j;
        bool up = ((i & k) == 0); // descending
        unsigned long long a = arr[i], b = arr[l];
        if ((a < b) == up) { arr[i] = b; arr[l] = a; }
      }
      __syncthreads();
    }
  }
  for (int i = t; i < PREK; i += 1024) {
    unsigned long long key = arr[i];
    unsigned sb = (unsigned)(key >> 32);
    topS[i] = __uint_as_float(sb);
    topI[i] = ~((unsigned)key);
    unsigned long long bal = __ballot(sb != 0);   // score > 0 <=> bits != 0
    if ((t & 63) == 0) validW[i >> 6] = bal;
  }
}

// ---- decode selected boxes ----
__global__ void k_decode(const float* __restrict__ cls, const float* __restrict__ box,
                         const float* __restrict__ dir, const float* __restrict__ anc,
                         const unsigned* __restrict__ topI,
                         float* __restrict__ tb, float4* __restrict__ b4,
                         unsigned* __restrict__ label) {
  int i = blockIdx.x * blockDim.x + threadIdx.x;
  if (i >= PREK) return;
  size_t idx = (size_t)topI[i];
  const float* a = anc + idx * 7;
  const float* b = box + idx * 7;
  float xa = a[0], ya = a[1], za = a[2], dxa = a[3], dya = a[4], dza = a[5], ra = a[6];
  float xt = b[0], yt = b[1], zt = b[2], dxt = b[3], dyt = b[4], dzt = b[5], rt = b[6];
  za = za + dza * 0.5f;
  float diag = sqrtf(dxa * dxa + dya * dya);
  float xg = xt * diag + xa;
  float yg = yt * diag + ya;
  float zg = zt * dza + za;
  float dxg = (float)exp((double)dxt) * dxa;
  float dyg = (float)exp((double)dyt) * dya;
  float dzg = (float)exp((double)dzt) * dza;
  float rg = rt + ra;
  zg = zg - dzg * 0.5f;
  float d0 = dir[idx * 2], d1 = dir[idx * 2 + 1];
  float dl = (d1 > d0) ? 1.0f : 0.0f;
  float val = rg - DIR_OFFSET;
  val = val - floorf(val / PERIOD) * PERIOD;
  float rot = val + DIR_OFFSET + PERIOD * dl;
  float l0 = cls[idx * 3 + 0];
  float l1 = cls[idx * 3 + 1];
  float l2 = cls[idx * 3 + 2];
  unsigned lab = 1;
  float bestl = l0;
  if (l1 > bestl) { bestl = l1; lab = 2; }
  if (l2 > bestl) { bestl = l2; lab = 3; }
  tb[i * 7 + 0] = xg; tb[i * 7 + 1] = yg; tb[i * 7 + 2] = zg;
  tb[i * 7 + 3] = dxg; tb[i * 7 + 4] = dyg; tb[i * 7 + 5] = dzg;
  tb[i * 7 + 6] = rot;
  float X1 = xg - dxg * 0.5f, X2 = xg + dxg * 0.5f;
  float Y1 = yg - dyg * 0.5f, Y2 = yg + dyg * 0.5f;
  b4[i] = make_float4(X1, Y1, X2, Y2);
  label[i] = lab;
}

// ---- pairwise IoU bitmask, LDS-staged, ballot-per-word ----
__global__ __launch_bounds__(256) void k_maskgen(const float4* __restrict__ b4,
                                                 unsigned long long* __restrict__ mask) {
  __shared__ float4 sb[PREK];   // 64 KB
  int t = threadIdx.x;
  for (int i = t; i < PREK; i += 256) sb[i] = b4[i];
  __syncthreads();
  int lane = t & 63, wv = t >> 6;
  for (int k = wv; k < 16; k += 4) {
    int r = blockIdx.x + (k << 8);
    float4 bi = sb[r];
    float A = (bi.z - bi.x) * (bi.w - bi.y);
    unsigned long long myword = 0;
    int w0 = r >> 6;
    for (int w = w0; w < 64; ++w) {
      int j = (w << 6) + lane;
      float4 bj = sb[j];
      float ix = fminf(bi.z, bj.z) - fmaxf(bi.x, bj.x); ix = fmaxf(ix, 0.0f);
      float iy = fminf(bi.w, bj.w) - fmaxf(bi.y, bj.y); iy = fmaxf(iy, 0.0f);
      float inter = ix * iy;
      float Aj = (bj.z - bj.x) * (bj.w - bj.y);
      float iou = inter / (A + Aj - inter + 1e-6f);
      unsigned long long word = __ballot(j > r && iou > IOU_THRESH);
      if (lane == w) myword = word;
    }
    mask[((size_t)r << 6) + lane] = myword;
  }
}

// ---- fused greedy NMS (wave 0, scalar resolution) + output build ----
__global__ __launch_bounds__(512) void k_tail(const float* __restrict__ topS,
                                              const float* __restrict__ tb,
                                              const unsigned* __restrict__ label,
                                              const unsigned long long* __restrict__ validW,
                                              const unsigned long long* __restrict__ mask,
                                              float* __restrict__ out) {
  __shared__ unsigned long long kwS[64];
  __shared__ int part[512];
  __shared__ short keptList[PREK];
  __shared__ short nonKept[PREK];
  int t = threadIdx.x;
  if (t < 64) {
    int lane = t;
    unsigned long long valid_l = validW[lane];
    unsigned long long removed = 0, keep_l = 0;
    // diag prefetch 2 ahead: m_cur for chunk c holds mask[c*64+lane][word c]
    unsigned long long m_cur = mask[((size_t)0 << 12) + ((size_t)lane << 6) + 0];
    unsigned long long m_n1  = mask[((size_t)1 << 12) + ((size_t)lane << 6) + 1];
    for (int c = 0; c < 64; ++c) {
      unsigned long long m_n2 = 0;
      if (c + 2 < 64)
        m_n2 = mask[((size_t)(c + 2) << 12) + ((size_t)lane << 6) + (c + 2)];
      unsigned long long remC = rdl64(removed, c);
      unsigned long long valC = rdl64(valid_l, c);
      unsigned long long pending = valC & ~remC;   // scalar (readlane results)
      unsigned long long kept = 0;
      unsigned mlo = (unsigned)m_cur, mhi = (unsigned)(m_cur >> 32);
      while (pending) {
        int b = __ffsll((long long)pending) - 1;
        b = __builtin_amdgcn_readfirstlane(b);
        kept |= (1ull << b);
        unsigned long long mb =
            ((unsigned long long)(unsigned)__builtin_amdgcn_readlane((int)mhi, b) << 32) |
            (unsigned long long)(unsigned)__builtin_amdgcn_readlane((int)mlo, b);
        pending &= (pending - 1);
        pending &= ~mb;
      }
      if (lane == c) keep_l = kept;
      // apply kept rows: lane l ORs word l (only words >= c still matter)
      bool act = (lane >= c);
      unsigned long long kw = kept;
      size_t rb = ((size_t)c << 12);
      while (kw) {
        unsigned long long v[16];
#pragma unroll
        for (int u = 0; u < 16; ++u) v[u] = 0;
#pragma unroll
        for (int u = 0; u < 16; ++u) {
          if (kw) {
            int b = __ffsll((long long)kw) - 1;
            kw &= (kw - 1);
            if (act) v[u] = mask[rb + ((size_t)b << 6) + lane];
          }
        }
        unsigned long long o = 0;
#pragma unroll
        for (int u = 0; u < 16; ++u) o |= v[u];
        removed |= o;
      }
      m_cur = m_n1;
      m_n1 = m_n2;
    }
    kwS[lane] = keep_l;
  }
  __syncthreads();
  // ---- output phase ----
  int base = t * 8;
  int cnt = 0;
  for (int e = 0; e < 8; ++e) {
    int i = base + e;
    cnt += (int)((kwS[i >> 6] >> (i & 63)) & 1ull);
  }
  part[t] = cnt;
  __syncthreads();
  for (int off = 1; off < 512; off <<= 1) {
    int v = part[t];
    int add = (t >= off) ? part[t - off] : 0;
    __syncthreads();
    part[t] = v + add;
    __syncthreads();
  }
  int kbase = part[t] - cnt;
  int nbase = base - kbase;
  for (int e = 0; e < 8; ++e) {
    int i = base + e;
    bool kp = ((kwS[i >> 6] >> (i & 63)) & 1ull) != 0;
    if (kp) keptList[kbase++] = (short)i;
    else nonKept[nbase++] = (short)i;
  }
  __syncthreads();
  int keptCount = part[511];
  for (int k = t; k < POSTK; k += 512) {
    int i;
    float s;
    if (k < keptCount) { i = keptList[k]; s = topS[i]; }
    else { i = nonKept[k - keptCount]; s = 0.0f; }
    for (int c = 0; c < 7; ++c) out[k * 8 + c] = tb[i * 7 + c];
    out[k * 8 + 7] = s;
    out[POSTK * 8 + k] = (float)label[i];
  }
}

extern "C" void kernel_launch(void* const* d_in, const int* in_sizes, int n_in,
                              void* d_out, int out_size, void* d_ws, size_t ws_size,
                              hipStream_t stream) {
  const float* cls = (const float*)d_in[0];
  const float* box = (const float*)d_in[1];
  const float* dir = (const float*)d_in[2];
  const float* anc = (const float*)d_in[3];
  float* out = (float*)d_out;
  char* ws = (char*)d_ws;
  if (ws_size < WS_NEED) return;

  float* scores = (float*)(ws + oScores);
  unsigned* hist12 = (unsigned*)(ws + oHist12);
  unsigned* histA = (unsigned*)(ws + oHistA);
  unsigned* histB = (unsigned*)(ws + oHistB);
  unsigned* meta = (unsigned*)(ws + oMeta);
  float* laS = (float*)(ws + oListAS);
  unsigned* laI = (unsigned*)(ws + oListAI);
  unsigned* lb = (unsigned*)(ws + oListB);
  float* topS = (float*)(ws + oTopS);
  unsigned* topI = (unsigned*)(ws + oTopI);
  float* tb = (float*)(ws + oTB);
  float4* b4 = (float4*)(ws + oB4);
  unsigned* label = (unsigned*)(ws + oLabel);
  unsigned long long* validW = (unsigned long long*)(ws + oValidW);
  unsigned long long* mask = (unsigned long long*)(ws + oMask);

  hipMemsetAsync(ws + oHist12, 0, (oListAS - oHist12), stream);

  k_scores<<<NG / 256, 256, 0, stream>>>((const float4*)cls, (float4*)scores, hist12);
  k_scan<<<1, 256, 0, stream>>>(hist12, meta, 4096, -1, 0, 1, 10);
  k_refine<<<NG / 256, 256, 0, stream>>>((const float4*)scores, histA, meta, 0);
  k_scan<<<1, 256, 0, stream>>>(histA, meta, 1024, 1, 2, 3, 11);
  k_refine<<<NG / 256, 256, 0, stream>>>((const float4*)scores, histB, meta, 1);
  k_scan<<<1, 256, 0, stream>>>(histB, meta, 1024, 3, 12, 5, 6);
  k_compact<<<NG / 256, 256, 0, stream>>>((const float4*)scores, meta, laS, laI, lb);
  k_select<<<1, 1024, 0, stream>>>(meta, laS, laI, lb, topS, topI, validW);
  k_decode<<<PREK / 256, 256, 0, stream>>>(cls, box, dir, anc, topI, tb, b4, label);
  k_maskgen<<<256, 256, 0, stream>>>(b4, mask);
  k_tail<<<1, 512, 0, stream>>>(topS, tb, label, validW, mask, out);
}